// Round 4
// baseline (139.680 us; speedup 1.0000x reference)
//
#include <hip/hip_runtime.h>

#define T_DIM 512
#define B_DIM 128
#define E_DIM 256
#define L_CAP 16
#define NEG_INF (-1e30f)

// Closed-form stack math (exact max-plus identity):
//   rc_t[tau] = S[t] + max_{m in [tau,t]} g[m],  S = incl. prefix sum of (d-u),
//   g[m] = d[m] - S[m].
//   W[t][tau] != 0 only at strict right-to-left records of g (NGL chain from t),
//   truncated once S[t] + g[m] >= 1.  Chains precompiled into (w, m) lists.

struct Node { float g; int ngl; };

// Kernel 1: per-b prep. Shuffle scan for S, sparse-table NGL, then walk each
// chain IN LDS and emit per-(t) gather lists (w,m) x L_CAP + aux record.
// aux = (cnt, tail_m (-1 if complete), tail_prev_bits, S_bits).
__global__ void __launch_bounds__(512) scan_prep(
    const float* __restrict__ u, const float* __restrict__ d,
    Node* __restrict__ nodes, float2* __restrict__ lists, int4* __restrict__ aux)
{
    const int b    = blockIdx.x;
    const int t    = threadIdx.x;
    const int lane = t & 63;
    const int w    = t >> 6;          // 8 waves

    __shared__ float wsum[8];
    __shared__ float wpre[8];
    __shared__ float M[10][T_DIM];    // M[k][i] = max g over [max(0,i-2^k+1), i]
    __shared__ int   ngl_s[T_DIM];
    __shared__ float2 stage[T_DIM * L_CAP];   // 64 KB list staging

    const float dv = d[t * B_DIM + b];
    float x = dv - u[t * B_DIM + b];

    // wave-level inclusive scan (6 shfl steps)
    #pragma unroll
    for (int off = 1; off < 64; off <<= 1) {
        float y = __shfl_up(x, off, 64);
        if (lane >= off) x += y;
    }
    if (lane == 63) wsum[w] = x;
    __syncthreads();
    if (t < 8) {
        float s = 0.f;
        for (int i = 0; i < t; ++i) s += wsum[i];
        wpre[t] = s;
    }
    __syncthreads();
    const float S = x + wpre[w];       // inclusive prefix sum of (d-u)
    const float g = dv - S;

    // sparse table (doubling window max); M[0] = g stays intact
    M[0][t] = g;
    __syncthreads();
    #pragma unroll
    for (int k = 1; k < 10; ++k) {
        int h = 1 << (k - 1);
        float left = (t >= h) ? M[k - 1][t - h] : NEG_INF;
        float mk = fmaxf(M[k - 1][t], left);
        __syncthreads();
        M[k][t] = mk;
        __syncthreads();
    }

    // binary descend: largest m < t with g[m] > g (strict); else -1
    int m = t - 1;
    #pragma unroll
    for (int k = 9; k >= 0; --k) {
        if (m >= 0 && M[k][m] <= g) m -= (1 << k);
    }
    if (m < 0) m = -1;
    ngl_s[t] = m;
    nodes[(b << 9) | t] = Node{g, m};   // fallback path only
    __syncthreads();

    // walk own chain in LDS, emit (w, m) pairs
    float2* mystage = &stage[t * L_CAP];
    float prev = 0.f;
    int mcur = t, cnt = 0, tailm = -1;
    float tailprev = 0.f;
    #pragma unroll 1
    for (;;) {
        float gm = M[0][mcur];
        float rc = S + gm;
        float cur = fminf(rc, 1.f);
        mystage[cnt] = make_float2(cur - prev, __int_as_float(mcur));
        ++cnt; prev = cur;
        int nx = ngl_s[mcur];
        if (rc >= 1.f || nx < 0) break;
        if (cnt == L_CAP) { tailm = nx; tailprev = prev; break; }
        mcur = nx;
    }
    aux[(b << 9) | t] = make_int4(cnt, tailm, __float_as_int(tailprev), __float_as_int(S));
    __syncthreads();

    // coalesced copy-out of lists (unused tail entries are garbage; never read)
    float4* gl = (float4*)(lists + (size_t)(b << 9) * L_CAP);
    const float4* st = (const float4*)stage;
    #pragma unroll
    for (int i = 0; i < (T_DIM * L_CAP) / 2 / 512; ++i)
        gl[i * 512 + t] = st[i * 512 + t];
}

// Kernel 2: one wave per (t,b). NO dependent loads: read the precompiled list
// (one 128B txn), then gather v rows in chunks of 4 INDEPENDENT loads,
// branchless predication (nothing for the compiler to exec-merge).
__global__ void __launch_bounds__(256) stack_read(
    const float* __restrict__ v, const Node* __restrict__ nodes,
    const float2* __restrict__ lists, const int4* __restrict__ aux,
    float* __restrict__ out)
{
    const int wid  = (blockIdx.x << 2) | (threadIdx.x >> 6);  // 0..65535
    const int lane = threadIdx.x & 63;
    const int b = wid >> 9;
    const int t = wid & 511;
    const int e4 = lane << 2;
    const float* __restrict__ vb = v + (size_t)b * E_DIM + e4;

    const int4 ax = aux[wid];                 // wave-uniform broadcast
    const int cnt = ax.x;

    // lanes 0..15 hold list entry (lane&15); one coalesced 128B read
    float2 pr = lists[(size_t)wid * L_CAP + (lane & 15)];
    float my_w = pr.x;
    int   my_m = __float_as_int(pr.y);

    float4 acc = {0.f, 0.f, 0.f, 0.f};
    const int nc = (cnt + 3) >> 2;
    #pragma unroll 1
    for (int c = 0; c < nc; ++c) {
        float wj[4]; float4 vj[4];
        #pragma unroll
        for (int j = 0; j < 4; ++j) {
            int idx = (c << 2) + j;
            int   mj = __shfl(my_m, idx, 64);
            float ww = __shfl(my_w, idx, 64);
            bool on = idx < cnt;
            mj = on ? mj : t;                 // always-valid row, weight 0
            wj[j] = on ? ww : 0.f;
            vj[j] = *(const float4*)(vb + (size_t)mj * (B_DIM * E_DIM));
        }
        #pragma unroll
        for (int j = 0; j < 4; ++j) {
            acc.x += wj[j] * vj[j].x; acc.y += wj[j] * vj[j].y;
            acc.z += wj[j] * vj[j].z; acc.w += wj[j] * vj[j].w;
        }
    }

    // exact fallback for chains longer than L_CAP (statistically absent)
    if (ax.y >= 0) {
        const float S = __int_as_float(ax.w);
        float prev = __int_as_float(ax.z);
        int m = ax.y;
        const Node* __restrict__ nb = nodes + (b << 9);
        while (true) {
            Node nd = nb[m];
            float rc = S + nd.g;
            float cur = fminf(rc, 1.f);
            float ww = cur - prev;
            float4 vv = *(const float4*)(vb + (size_t)m * (B_DIM * E_DIM));
            acc.x += ww * vv.x; acc.y += ww * vv.y;
            acc.z += ww * vv.z; acc.w += ww * vv.w;
            prev = cur;
            if (rc >= 1.f || nd.ngl < 0) break;
            m = nd.ngl;
        }
    }

    *(float4*)(out + ((size_t)t * B_DIM + b) * E_DIM + e4) = acc;
}

extern "C" void kernel_launch(void* const* d_in, const int* in_sizes, int n_in,
                              void* d_out, int out_size, void* d_ws, size_t ws_size,
                              hipStream_t stream) {
    const float* v = (const float*)d_in[0];
    const float* u = (const float*)d_in[1];
    const float* d = (const float*)d_in[2];
    float* out = (float*)d_out;

    char* ws = (char*)d_ws;
    Node*   node = (Node*)ws;                                  // 512 KB
    float2* list = (float2*)(ws + (1 << 19));                  // 8 MB
    int4*   aux  = (int4*)(ws + (1 << 19) + (1 << 23));        // 1 MB

    scan_prep<<<dim3(B_DIM), 512, 0, stream>>>(u, d, node, list, aux);
    stack_read<<<dim3((T_DIM * B_DIM) / 4), 256, 0, stream>>>(v, node, list, aux, out);
}